// Round 2
// baseline (588.928 us; speedup 1.0000x reference)
//
#include <hip/hip_runtime.h>
#include <hip/hip_bf16.h>
#include <stdint.h>

typedef __attribute__((ext_vector_type(4))) float f32x4;
typedef __attribute__((ext_vector_type(8))) short bf16x8;
typedef __attribute__((ext_vector_type(4))) float float4v;

static constexpr int KD    = 1024;   // hidden dim
static constexpr int ND    = 2048;   // expert out dim (gate+up)
static constexpr int NE    = 8;      // experts
static constexpr int MROWS = 16384;  // hidden rows
static constexpr int RFLAT = 32768;  // M * topk
static constexpr int OUTN  = 1024;   // output cols (ND/2)

// ws layout (bytes):
//   [0 .. 128)        : ints: cnt[8] @0, cursor[8] @32, offs[9] @64, mode @124 (wsi[31])
//   [1024 .. 132096)  : rowlist[32768] int
//   [262144 .. +32MiB): H bf16 (16384 x 1024)
//   [+32MiB .. +64MiB): W^T bf16 (8 x 2048 x 1024)  [e][n][k]
static constexpr size_t WS_ROWLIST = 1024;
static constexpr size_t WS_HB      = 262144;
static constexpr size_t WS_WT      = 262144 + (size_t)33554432;

__device__ __forceinline__ unsigned short f2bf(float f) {
  uint32_t u = __float_as_uint(f);
  uint32_t r = (u + 0x7FFFu + ((u >> 16) & 1u)) >> 16;
  return (unsigned short)r;
}

__device__ __forceinline__ void gload16(const void* g, void* l) {
  __builtin_amdgcn_global_load_lds(
      (__attribute__((address_space(1))) void*)(void*)g,
      (__attribute__((address_space(3))) void*)l, 16, 0, 0);
}

// Detect whether ids buffer is int32 (harness-converted) or raw int64.
// int64 little-endian: slots 1,3,5,... (high words of values 0..7) are all 0.
// Genuine int32 uniform 0..7: some odd slot nonzero with prob 1 - 8^-16384.
__global__ void k_detect(const int* __restrict__ ids32, int* __restrict__ wsi) {
  int t = blockIdx.x * 256 + threadIdx.x;  // scans odd slots of first 32768 ints
  int i = 2 * t + 1;
  if (i < RFLAT && ids32[i] != 0) atomicOr(&wsi[31], 1);
}

__device__ __forceinline__ int read_id(const int* ids32, int t, int mode) {
  return (mode ? ids32[t] : ids32[2 * t]) & 7;
}

__global__ void k_count(const int* __restrict__ ids, int* __restrict__ wsi) {
  int t = blockIdx.x * 256 + threadIdx.x;
  int mode = wsi[31];
  if (t < RFLAT) atomicAdd(&wsi[read_id(ids, t, mode)], 1);
}

__global__ void k_scan(int* wsi) {
  if (threadIdx.x == 0) {
    int o = 0;
    for (int e = 0; e < NE; ++e) {
      wsi[16 + e] = o;  // offs
      wsi[8 + e]  = o;  // cursor
      o += wsi[e];
    }
    wsi[16 + NE] = o;
  }
}

__global__ void k_scatter(const int* __restrict__ ids, int* __restrict__ wsi,
                          int* __restrict__ rowlist) {
  int t = blockIdx.x * 256 + threadIdx.x;
  int mode = wsi[31];
  if (t < RFLAT) {
    int e = read_id(ids, t, mode);
    int p = atomicAdd(&wsi[8 + e], 1);
    rowlist[p] = t;
  }
}

__global__ void k_cvtH(const float* __restrict__ H, unsigned short* __restrict__ Hb) {
  const int n4 = (MROWS * KD) / 4;
  const int stride = gridDim.x * blockDim.x;
  for (int i = blockIdx.x * blockDim.x + threadIdx.x; i < n4; i += stride) {
    float4v v = ((const float4v*)H)[i];
    ushort4 o;
    o.x = f2bf(v.x); o.y = f2bf(v.y); o.z = f2bf(v.z); o.w = f2bf(v.w);
    ((ushort4*)Hb)[i] = o;
  }
}

// Transpose + convert: W[e][k][n] fp32 -> Wt[e][n][k] bf16
__global__ void k_cvtW(const float* __restrict__ W, unsigned short* __restrict__ Wt) {
  __shared__ float tile[32][33];
  const int e  = blockIdx.z;
  const int n0 = blockIdx.x * 32;
  const int k0 = blockIdx.y * 32;
  const float* Wp = W + (size_t)e * KD * ND;
  #pragma unroll
  for (int i = threadIdx.y; i < 32; i += 8)
    tile[i][threadIdx.x] = Wp[(size_t)(k0 + i) * ND + n0 + threadIdx.x];
  __syncthreads();
  unsigned short* Wo = Wt + (size_t)e * ND * KD;
  #pragma unroll
  for (int i = threadIdx.y; i < 32; i += 8)
    Wo[(size_t)(n0 + i) * KD + k0 + threadIdx.x] = f2bf(tile[threadIdx.x][i]);
}

// Grouped GEMM + fused silu*up epilogue.
// Block: 128 gathered flat-rows x 128 output cols (= 256 weight cols: gate+up).
// 256 threads = 4 waves (wr x wc); per wave 64 rows x 64 out cols, acc[4][8]
// (h<4 gate, h>=4 up) so the gate/up pair is thread-local for fused silu.
// LDS [kchunk][row][8 bf16]: linear global_load_lds dest, 2-way-free ds_read_b128.
__global__ __launch_bounds__(256, 2) void k_gemm(
    const unsigned short* __restrict__ Hb, const unsigned short* __restrict__ Wt,
    const int* __restrict__ wsi, const int* __restrict__ rowlist,
    float* __restrict__ Out) {
  const int e = blockIdx.z;
  const int cnt = wsi[e];
  const int tile_base = blockIdx.y * 128;
  if (tile_base >= cnt) return;
  const int tile_cnt = min(128, cnt - tile_base);
  const int off = wsi[16 + e] + tile_base;
  const int c0 = blockIdx.x * 128;

  __shared__ unsigned short sA[4][128][8];  // 8 KiB
  __shared__ unsigned short sB[4][256][8];  // 16 KiB
  __shared__ int s_rows[128];

  const int t = threadIdx.x;
  if (t < 128) s_rows[t] = rowlist[off + min(t, tile_cnt - 1)];
  __syncthreads();

  const char* hb = (const char*)Hb;
  const char* wb = (const char*)Wt;

  // A staging: flat row t reads hidden row (t >> 1)  <-- h_rep = repeat(H, topk)
  const int arow = t & 127;
  const size_t abase = (size_t)(s_rows[arow] >> 1) * (KD * 2);
  const char* srcA0 = hb + abase + (size_t)((t >> 7) * 16);
  const char* srcA1 = hb + abase + (size_t)((2 + (t >> 7)) * 16);
  // B staging: n_local t<128 -> gate col c0+t ; t>=128 -> up col 1024+c0+(t-128)
  const int ngl = (t < 128) ? (c0 + t) : (OUTN + c0 + (t - 128));
  const char* srcB = wb + ((size_t)e * ND + ngl) * (KD * 2);

  char* lA = (char*)sA;
  char* lB = (char*)sB;
  char* dA0 = lA + t * 16;
  char* dA1 = lA + 4096 + t * 16;
  char* dB0 = lB + t * 16;
  char* dB1 = lB + 4096 + t * 16;
  char* dB2 = lB + 8192 + t * 16;
  char* dB3 = lB + 12288 + t * 16;

  const int lane = t & 63;
  const int wid = t >> 6;
  const int wr = wid >> 1, wc = wid & 1;
  const int kc = lane >> 4, l15 = lane & 15;

  f32x4 acc[4][8];
  #pragma unroll
  for (int m = 0; m < 4; ++m)
    #pragma unroll
    for (int h = 0; h < 8; ++h)
      acc[m][h] = (f32x4){0.f, 0.f, 0.f, 0.f};

  const char* sAb = (const char*)sA;
  const char* sBb = (const char*)sB;
  int aoff[4], boff[8];
  #pragma unroll
  for (int m = 0; m < 4; ++m)
    aoff[m] = kc * 2048 + (wr * 64 + m * 16 + l15) * 16;
  #pragma unroll
  for (int h = 0; h < 8; ++h) {
    int nloc = ((h < 4) ? (wc * 64 + h * 16) : (128 + wc * 64 + (h - 4) * 16)) + l15;
    boff[h] = kc * 4096 + nloc * 16;
  }

  for (int ks = 0; ks < KD / 32; ++ks) {
    const size_t go = (size_t)ks * 64;
    gload16(srcA0 + go, dA0);
    gload16(srcA1 + go, dA1);
    gload16(srcB + go,      dB0);
    gload16(srcB + go + 16, dB1);
    gload16(srcB + go + 32, dB2);
    gload16(srcB + go + 48, dB3);
    __syncthreads();
    bf16x8 af[4], bfr[8];
    #pragma unroll
    for (int m = 0; m < 4; ++m) af[m] = *(const bf16x8*)(sAb + aoff[m]);
    #pragma unroll
    for (int h = 0; h < 8; ++h) bfr[h] = *(const bf16x8*)(sBb + boff[h]);
    #pragma unroll
    for (int m = 0; m < 4; ++m)
      #pragma unroll
      for (int h = 0; h < 8; ++h)
        acc[m][h] = __builtin_amdgcn_mfma_f32_16x16x32_bf16(af[m], bfr[h], acc[m][h], 0, 0, 0);
    __syncthreads();
  }

  // Fused epilogue: out[flat_row, c] = silu(gate)*up
  #pragma unroll
  for (int m = 0; m < 4; ++m) {
    const int rbase = wr * 64 + m * 16 + (lane >> 4) * 4;
    #pragma unroll
    for (int i = 0; i < 4; ++i) {
      const int rl = rbase + i;
      if (rl < tile_cnt) {
        const size_t orow = (size_t)s_rows[rl] * OUTN;
        #pragma unroll
        for (int h = 0; h < 4; ++h) {
          float g = acc[m][h][i];
          float u = acc[m][h + 4][i];
          float s = g / (1.0f + __expf(-g)) * u;
          Out[orow + c0 + wc * 64 + h * 16 + l15] = s;
        }
      }
    }
  }
}

extern "C" void kernel_launch(void* const* d_in, const int* in_sizes, int n_in,
                              void* d_out, int out_size, void* d_ws, size_t ws_size,
                              hipStream_t stream) {
  const float* H  = (const float*)d_in[0];
  const float* W  = (const float*)d_in[1];
  const int* ids  = (const int*)d_in[2];
  float* Out      = (float*)d_out;
  char* ws        = (char*)d_ws;
  int* wsi        = (int*)ws;
  int* rowlist    = (int*)(ws + WS_ROWLIST);
  unsigned short* Hb = (unsigned short*)(ws + WS_HB);
  unsigned short* Wt = (unsigned short*)(ws + WS_WT);

  hipMemsetAsync(ws, 0, 1024, stream);
  k_detect<<<RFLAT / 2 / 256, 256, 0, stream>>>(ids, wsi);
  k_count<<<RFLAT / 256, 256, 0, stream>>>(ids, wsi);
  k_scan<<<1, 64, 0, stream>>>(wsi);
  k_scatter<<<RFLAT / 256, 256, 0, stream>>>(ids, wsi, rowlist);
  k_cvtH<<<2048, 256, 0, stream>>>(H, Hb);
  k_cvtW<<<dim3(ND / 32, KD / 32, NE), dim3(32, 8), 0, stream>>>(W, Wt);
  k_gemm<<<dim3(OUTN / 128, RFLAT / 128, NE), 256, 0, stream>>>(Hb, Wt, wsi, rowlist, Out);
}

// Round 3
// 367.872 us; speedup vs baseline: 1.6009x; 1.6009x over previous
//
#include <hip/hip_runtime.h>
#include <hip/hip_bf16.h>
#include <stdint.h>

typedef __attribute__((ext_vector_type(4))) float f32x4;
typedef __attribute__((ext_vector_type(8))) short bf16x8;
typedef __attribute__((ext_vector_type(4))) float float4v;

static constexpr int KD    = 1024;   // hidden dim
static constexpr int ND    = 2048;   // expert out dim (gate+up)
static constexpr int NE    = 8;      // experts
static constexpr int MROWS = 16384;  // hidden rows
static constexpr int RFLAT = 32768;  // M * topk
static constexpr int OUTN  = 1024;   // output cols (ND/2)

// ws ints: cnt[8]@0, cursor[8]@8, offs[9]@16, mode@31, tileoff[9]@40
static constexpr size_t WS_ROWLIST = 1024;
static constexpr size_t WS_HB      = 262144;
static constexpr size_t WS_WT      = 262144 + (size_t)33554432;

__device__ __forceinline__ unsigned short f2bf(float f) {
  uint32_t u = __float_as_uint(f);
  uint32_t r = (u + 0x7FFFu + ((u >> 16) & 1u)) >> 16;
  return (unsigned short)r;
}

__device__ __forceinline__ void gload16(const void* g, void* l) {
  __builtin_amdgcn_global_load_lds(
      (__attribute__((address_space(1))) void*)(void*)g,
      (__attribute__((address_space(3))) void*)l, 16, 0, 0);
}

// Detect int32-converted vs raw-int64 ids (odd 32-bit slots all zero => int64).
__global__ void k_detect(const int* __restrict__ ids32, int* __restrict__ wsi) {
  int t = blockIdx.x * 256 + threadIdx.x;
  int i = 2 * t + 1;
  if (i < RFLAT && ids32[i] != 0) atomicOr(&wsi[31], 1);
}

__device__ __forceinline__ int read_id(const int* ids32, int t, int mode) {
  return (mode ? ids32[t] : ids32[2 * t]) & 7;
}

// LDS-histogram count: 64 blocks x 512 elems -> 512 global atomics.
__global__ void k_count(const int* __restrict__ ids, int* __restrict__ wsi) {
  __shared__ int h[8];
  const int tid = threadIdx.x;
  if (tid < 8) h[tid] = 0;
  __syncthreads();
  const int mode = wsi[31];
  const int base = blockIdx.x * 512 + tid;
  atomicAdd(&h[read_id(ids, base, mode)], 1);
  atomicAdd(&h[read_id(ids, base + 256, mode)], 1);
  __syncthreads();
  if (tid < 8 && h[tid]) atomicAdd(&wsi[tid], h[tid]);
}

__global__ void k_scan(int* wsi) {
  if (threadIdx.x == 0) {
    int o = 0, to = 0;
    for (int e = 0; e < NE; ++e) {
      int c = wsi[e];
      wsi[16 + e] = o;   // offs
      wsi[8 + e]  = o;   // cursor
      wsi[40 + e] = to;  // tile offset
      o += c;
      to += (c + 127) / 128;
    }
    wsi[16 + NE] = o;
    wsi[40 + NE] = to;
  }
}

// LDS-histogram scatter: per-block base + local rank -> 1024 global atomics.
__global__ void k_scatter(const int* __restrict__ ids, int* __restrict__ wsi,
                          int* __restrict__ rowlist) {
  __shared__ int h[8], base[8], c2[8];
  const int tid = threadIdx.x;
  if (tid < 8) { h[tid] = 0; c2[tid] = 0; }
  __syncthreads();
  const int mode = wsi[31];
  const int t = blockIdx.x * 256 + tid;
  const int e = read_id(ids, t, mode);
  atomicAdd(&h[e], 1);
  __syncthreads();
  if (tid < 8 && h[tid]) base[tid] = atomicAdd(&wsi[8 + tid], h[tid]);
  __syncthreads();
  const int r = atomicAdd(&c2[e], 1);
  rowlist[base[e] + r] = t;
}

__global__ void k_cvtH(const float* __restrict__ H, unsigned short* __restrict__ Hb) {
  const int n4 = (MROWS * KD) / 4;
  const int stride = gridDim.x * blockDim.x;
  for (int i = blockIdx.x * blockDim.x + threadIdx.x; i < n4; i += stride) {
    float4v v = ((const float4v*)H)[i];
    ushort4 o;
    o.x = f2bf(v.x); o.y = f2bf(v.y); o.z = f2bf(v.z); o.w = f2bf(v.w);
    ((ushort4*)Hb)[i] = o;
  }
}

// Transpose + convert: W[e][k][n] fp32 -> Wt[e][n][k] bf16 (64x64 tiles).
__global__ void k_cvtW(const float* __restrict__ W, unsigned short* __restrict__ Wt) {
  __shared__ float tile[64][65];
  const int e  = blockIdx.z;
  const int n0 = blockIdx.x * 64;
  const int k0 = blockIdx.y * 64;
  const int tx = threadIdx.x, ty = threadIdx.y;
  const float* Wp = W + (size_t)e * KD * ND;
  #pragma unroll
  for (int i = ty; i < 64; i += 8)
    tile[i][tx] = Wp[(size_t)(k0 + i) * ND + n0 + tx];
  __syncthreads();
  unsigned short* Wo = Wt + (size_t)e * ND * KD;
  #pragma unroll
  for (int i = ty; i < 64; i += 8)
    Wo[(size_t)(n0 + i) * KD + k0 + tx] = f2bf(tile[tx][i]);
}

// Grouped GEMM, m97 structure: 128 rows x 128 weight-cols (64 gate + 64 up),
// BK=64, 4 waves, acc[4][4]. Flat grid with XCD swizzle: xcd = bid&7 owns
// row-tiles rt == xcd (mod 8); within an XCD, col-blocks vary fastest so the
// 256KB A-tile stays L2-resident across all 16 col-blocks.
__global__ __launch_bounds__(256, 2) void k_gemm(
    const unsigned short* __restrict__ Hb, const unsigned short* __restrict__ Wt,
    const int* __restrict__ wsi, const int* __restrict__ rowlist,
    float* __restrict__ Out) {
  const int bid = blockIdx.x;
  const int xcd = bid & 7;
  const int jj  = bid >> 3;
  const int colblk = jj & 15;
  const int rt = xcd + (jj >> 4) * 8;
  if (rt >= wsi[48]) return;
  int e = 0;
  #pragma unroll
  for (int q = 1; q < 8; ++q)
    if (rt >= wsi[40 + q]) e = q;
  const int cnt = wsi[e];
  const int tile_base = (rt - wsi[40 + e]) * 128;
  const int tile_cnt = min(128, cnt - tile_base);
  const int off = wsi[16 + e] + tile_base;
  const int c0 = colblk * 64;

  __shared__ unsigned short sA[8][128][8];  // [kchunk][row][8] 16 KiB
  __shared__ unsigned short sB[8][128][8];  // [kchunk][col][8] 16 KiB
  __shared__ int s_rows[128];

  const int t = threadIdx.x;
  if (t < 128) s_rows[t] = rowlist[off + min(t, tile_cnt - 1)];
  __syncthreads();

  // A: flat row -> hidden row (>>1, topk repeat). 4 x 16B per thread per K-step.
  const size_t abase = (size_t)(s_rows[t & 127] >> 1) * (KD * 2);
  const char* srcA = (const char*)Hb + abase + (size_t)((t >> 7) * 16);
  // B: col<64 gate (c0+col), col>=64 up (1024+c0+col-64).
  const int col = t & 127;
  const int ngl = (col < 64) ? (c0 + col) : (OUTN + c0 + (col - 64));
  const char* srcB = (const char*)Wt + ((size_t)e * ND + ngl) * (KD * 2) +
                     (size_t)((t >> 7) * 16);
  char* dA = (char*)sA + t * 16;
  char* dB = (char*)sB + t * 16;

  const int lane = t & 63;
  const int wid = t >> 6;
  const int wr = wid >> 1, wc = wid & 1;
  const int kc = lane >> 4, l15 = lane & 15;

  f32x4 acc[4][4];
  #pragma unroll
  for (int m = 0; m < 4; ++m)
    #pragma unroll
    for (int h = 0; h < 4; ++h)
      acc[m][h] = (f32x4){0.f, 0.f, 0.f, 0.f};

  int aoff[2][4], boff[2][4];
  #pragma unroll
  for (int q = 0; q < 2; ++q) {
    #pragma unroll
    for (int m = 0; m < 4; ++m)
      aoff[q][m] = (q * 4 + kc) * 2048 + (wr * 64 + m * 16 + l15) * 16;
    #pragma unroll
    for (int h = 0; h < 4; ++h) {
      int col_loc = (h < 2) ? (wc * 32 + h * 16) : (64 + wc * 32 + (h - 2) * 16);
      boff[q][h] = (q * 4 + kc) * 2048 + (col_loc + l15) * 16;
    }
  }

  const char* sAb = (const char*)sA;
  const char* sBb = (const char*)sB;

  for (int ks = 0; ks < KD / 64; ++ks) {
    const size_t go = (size_t)ks * 128;
    #pragma unroll
    for (int u = 0; u < 4; ++u) {
      gload16(srcA + go + u * 32, dA + u * 4096);
      gload16(srcB + go + u * 32, dB + u * 4096);
    }
    __syncthreads();
    bf16x8 af[2][4], bfv[2][4];
    #pragma unroll
    for (int q = 0; q < 2; ++q) {
      #pragma unroll
      for (int m = 0; m < 4; ++m) af[q][m] = *(const bf16x8*)(sAb + aoff[q][m]);
      #pragma unroll
      for (int h = 0; h < 4; ++h) bfv[q][h] = *(const bf16x8*)(sBb + boff[q][h]);
    }
    #pragma unroll
    for (int q = 0; q < 2; ++q)
      #pragma unroll
      for (int m = 0; m < 4; ++m)
        #pragma unroll
        for (int h = 0; h < 4; ++h)
          acc[m][h] = __builtin_amdgcn_mfma_f32_16x16x32_bf16(af[q][m], bfv[q][h], acc[m][h], 0, 0, 0);
    __syncthreads();
  }

  // Fused epilogue: gate = acc[m][h], up = acc[m][h+2]
  #pragma unroll
  for (int m = 0; m < 4; ++m) {
    const int rbase = wr * 64 + m * 16 + kc * 4;
    #pragma unroll
    for (int i = 0; i < 4; ++i) {
      const int rl = rbase + i;
      if (rl < tile_cnt) {
        const size_t orow = (size_t)s_rows[rl] * OUTN;
        #pragma unroll
        for (int h = 0; h < 2; ++h) {
          float g = acc[m][h][i];
          float u = acc[m][h + 2][i];
          float s = g / (1.0f + __expf(-g)) * u;
          Out[orow + c0 + wc * 32 + h * 16 + l15] = s;
        }
      }
    }
  }
}

extern "C" void kernel_launch(void* const* d_in, const int* in_sizes, int n_in,
                              void* d_out, int out_size, void* d_ws, size_t ws_size,
                              hipStream_t stream) {
  const float* H  = (const float*)d_in[0];
  const float* W  = (const float*)d_in[1];
  const int* ids  = (const int*)d_in[2];
  float* Out      = (float*)d_out;
  char* ws        = (char*)d_ws;
  int* wsi        = (int*)ws;
  int* rowlist    = (int*)(ws + WS_ROWLIST);
  unsigned short* Hb = (unsigned short*)(ws + WS_HB);
  unsigned short* Wt = (unsigned short*)(ws + WS_WT);

  hipMemsetAsync(ws, 0, 1024, stream);
  k_detect<<<RFLAT / 2 / 256, 256, 0, stream>>>(ids, wsi);
  k_count<<<RFLAT / 512, 256, 0, stream>>>(ids, wsi);
  k_scan<<<1, 64, 0, stream>>>(wsi);
  k_scatter<<<RFLAT / 256, 256, 0, stream>>>(ids, wsi, rowlist);
  k_cvtH<<<2048, 256, 0, stream>>>(H, Hb);
  k_cvtW<<<dim3(ND / 64, KD / 64, NE), dim3(64, 8), 0, stream>>>(W, Wt);
  // 264 row-tile slots (sum ceil(cnt_e/128) <= 263), 16 col-blocks, x8 XCD lanes
  k_gemm<<<8 * 33 * 16, 256, 0, stream>>>(Hb, Wt, wsi, rowlist, Out);
}